// Round 7
// baseline (343.408 us; speedup 1.0000x reference)
//
#include <hip/hip_runtime.h>
#include <cstdint>
#include <cstddef>

#define D_MODEL 1024
#define N_HEADS 16
#define HEAD_DIM 64
#define BATCH 4
#define SEQ 2048
#define M_TOTAL (BATCH * SEQ)   // 8192

typedef __attribute__((ext_vector_type(8))) short bf16x8;    // 8 bf16 = 4 VGPRs
typedef __attribute__((ext_vector_type(4))) float f32x4;
typedef __attribute__((ext_vector_type(16))) float f32x16;

// scale = 1/sqrt(64) * log2(e), folded into Q projection (softmax in exp2 domain)
#define Q_SCALE 0.18033688011112042f

__device__ __forceinline__ unsigned short f2bu(float f) {   // RNE
    union { float f; unsigned u; } x; x.f = f;
    unsigned r = x.u + 0x7FFFu + ((x.u >> 16) & 1u);
    return (unsigned short)(r >> 16);
}
__device__ __forceinline__ unsigned short f2bu_fast(float f) {  // round-half-up (P in [0,1])
    union { float f; unsigned u; } x; x.f = f;
    return (unsigned short)((x.u + 0x8000u) >> 16);
}

__device__ __forceinline__ void async16(void* lds, const void* g) {
    __builtin_amdgcn_global_load_lds(
        (const __attribute__((address_space(1))) void*)g,
        (__attribute__((address_space(3))) void*)lds, 16, 0, 0);
}

// ---------------------------------------------------------------------------
// One fused fp32 -> bf16 cast for x + 4 weights (contiguous dst in ws).
// ---------------------------------------------------------------------------
__global__ __launch_bounds__(256) void cast_all(const float* __restrict__ x,
                                                const float* __restrict__ wq,
                                                const float* __restrict__ wk,
                                                const float* __restrict__ wv,
                                                const float* __restrict__ wo,
                                                unsigned short* __restrict__ dst) {
    const size_t NE = (size_t)M_TOTAL * D_MODEL;
    const size_t WE = (size_t)D_MODEL * D_MODEL;
    size_t i4 = (size_t)blockIdx.x * 256 + threadIdx.x;
    size_t e = i4 * 4;
    const float* src; size_t off;
    if (e < NE) { src = x; off = e; }
    else {
        size_t t = e - NE;
        int r = (int)(t / WE); off = t - (size_t)r * WE;
        src = (r == 0) ? wq : (r == 1) ? wk : (r == 2) ? wv : wo;
    }
    float4 v = *(const float4*)(src + off);
    ushort4 o;
    o.x = f2bu(v.x); o.y = f2bu(v.y); o.z = f2bu(v.z); o.w = f2bu(v.w);
    ((ushort4*)dst)[i4] = o;
}

// ---------------------------------------------------------------------------
// Fused Q/K/V projection. sel 0: Q (pre-scaled by Q_SCALE), sel 1: K,
// sel 2: V written TRANSPOSED into Vt[bh][d][s].
// m97-style: 128x128 tile, BK=32, global_load_lds(16B), XOR chunk swizzle.
// ---------------------------------------------------------------------------
__global__ __launch_bounds__(256) void qkv_gemm(const unsigned short* __restrict__ X,
                                                const unsigned short* __restrict__ W0,
                                                const unsigned short* __restrict__ W1,
                                                const unsigned short* __restrict__ W2,
                                                unsigned short* __restrict__ Y0,
                                                unsigned short* __restrict__ Y1,
                                                unsigned short* __restrict__ Vt) {
    __shared__ short As[128 * 32];
    __shared__ short Bs[128 * 32];

    const int sel = blockIdx.x >> 3;
    const unsigned short* W = (sel == 0) ? W0 : (sel == 1) ? W1 : W2;
    const float scl = (sel == 0) ? Q_SCALE : 1.0f;

    const int tid = threadIdx.x;
    const int w = tid >> 6, lane = tid & 63, quad = lane >> 4, l15 = lane & 15;
    const int wm = w & 1, wn = w >> 1;
    const int rowBase = blockIdx.y * 128;
    const int colBase = (blockIdx.x & 7) * 128;

    f32x4 acc[4][4];
#pragma unroll
    for (int mi = 0; mi < 4; ++mi)
#pragma unroll
        for (int ni = 0; ni < 4; ++ni)
#pragma unroll
            for (int e = 0; e < 4; ++e) acc[mi][ni][e] = 0.f;

    for (int k0 = 0; k0 < 1024; k0 += 32) {
        __syncthreads();
#pragma unroll
        for (int l = 0; l < 2; ++l) {
            int c = tid + l * 256;
            int row = c >> 2, ccs = c & 3;
            int cc = ccs ^ ((row >> 1) & 3);
            async16((char*)As + c * 16, X + (size_t)(rowBase + row) * 1024 + k0 + cc * 8);
            async16((char*)Bs + c * 16, W + (size_t)(colBase + row) * 1024 + k0 + cc * 8);
        }
        __syncthreads();

        bf16x8 a[4], b[4];
#pragma unroll
        for (int mi = 0; mi < 4; ++mi) {
            int r = wm * 64 + mi * 16 + l15;
            int slot = quad ^ ((r >> 1) & 3);
            a[mi] = *(const bf16x8*)&As[r * 32 + slot * 8];
        }
#pragma unroll
        for (int ni = 0; ni < 4; ++ni) {
            int r = wn * 64 + ni * 16 + l15;
            int slot = quad ^ ((r >> 1) & 3);
            b[ni] = *(const bf16x8*)&Bs[r * 32 + slot * 8];
        }
#pragma unroll
        for (int mi = 0; mi < 4; ++mi)
#pragma unroll
            for (int ni = 0; ni < 4; ++ni)
                acc[mi][ni] = __builtin_amdgcn_mfma_f32_16x16x32_bf16(a[mi], b[ni], acc[mi][ni], 0, 0, 0);
    }

    if (sel != 2) {
        unsigned short* Y = (sel == 0) ? Y0 : Y1;
#pragma unroll
        for (int mi = 0; mi < 4; ++mi)
#pragma unroll
            for (int ni = 0; ni < 4; ++ni)
#pragma unroll
                for (int reg = 0; reg < 4; ++reg) {
                    int row = rowBase + wm * 64 + mi * 16 + quad * 4 + reg;
                    int col = colBase + wn * 64 + ni * 16 + l15;
                    Y[(size_t)row * 1024 + col] = f2bu(acc[mi][ni][reg] * scl);
                }
    } else {
        // transposed V write: Vt[((b*16+h)*64+d)*SEQ + s], 4 consecutive s per store
#pragma unroll
        for (int mi = 0; mi < 4; ++mi) {
            int row0 = rowBase + wm * 64 + mi * 16 + quad * 4;   // reg 0 row
            int bb = row0 >> 11;
            int s0 = row0 & 2047;
#pragma unroll
            for (int ni = 0; ni < 4; ++ni) {
                int col = colBase + wn * 64 + ni * 16 + l15;
                int hh = col >> 6, dd = col & 63;
                ushort4 pk;
                pk.x = f2bu(acc[mi][ni][0]); pk.y = f2bu(acc[mi][ni][1]);
                pk.z = f2bu(acc[mi][ni][2]); pk.w = f2bu(acc[mi][ni][3]);
                *(ushort4*)(Vt + (((size_t)bb * 16 + hh) * 64 + dd) * SEQ + s0) = pk;
            }
        }
    }
}

// ---------------------------------------------------------------------------
// Output projection: out[M,1024] = CTX @ Wo^T, fp32 out.
// ---------------------------------------------------------------------------
__global__ __launch_bounds__(256) void out_gemm(const unsigned short* __restrict__ X,
                                                const unsigned short* __restrict__ W,
                                                float* __restrict__ Y) {
    __shared__ short As[128 * 32];
    __shared__ short Bs[128 * 32];

    const int tid = threadIdx.x;
    const int w = tid >> 6, lane = tid & 63, quad = lane >> 4, l15 = lane & 15;
    const int wm = w & 1, wn = w >> 1;
    const int rowBase = blockIdx.y * 128;
    const int colBase = blockIdx.x * 128;

    f32x4 acc[4][4];
#pragma unroll
    for (int mi = 0; mi < 4; ++mi)
#pragma unroll
        for (int ni = 0; ni < 4; ++ni)
#pragma unroll
            for (int e = 0; e < 4; ++e) acc[mi][ni][e] = 0.f;

    for (int k0 = 0; k0 < 1024; k0 += 32) {
        __syncthreads();
#pragma unroll
        for (int l = 0; l < 2; ++l) {
            int c = tid + l * 256;
            int row = c >> 2, ccs = c & 3;
            int cc = ccs ^ ((row >> 1) & 3);
            async16((char*)As + c * 16, X + (size_t)(rowBase + row) * 1024 + k0 + cc * 8);
            async16((char*)Bs + c * 16, W + (size_t)(colBase + row) * 1024 + k0 + cc * 8);
        }
        __syncthreads();

        bf16x8 a[4], b[4];
#pragma unroll
        for (int mi = 0; mi < 4; ++mi) {
            int r = wm * 64 + mi * 16 + l15;
            int slot = quad ^ ((r >> 1) & 3);
            a[mi] = *(const bf16x8*)&As[r * 32 + slot * 8];
        }
#pragma unroll
        for (int ni = 0; ni < 4; ++ni) {
            int r = wn * 64 + ni * 16 + l15;
            int slot = quad ^ ((r >> 1) & 3);
            b[ni] = *(const bf16x8*)&Bs[r * 32 + slot * 8];
        }
#pragma unroll
        for (int mi = 0; mi < 4; ++mi)
#pragma unroll
            for (int ni = 0; ni < 4; ++ni)
                acc[mi][ni] = __builtin_amdgcn_mfma_f32_16x16x32_bf16(a[mi], b[ni], acc[mi][ni], 0, 0, 0);
    }

#pragma unroll
    for (int mi = 0; mi < 4; ++mi)
#pragma unroll
        for (int ni = 0; ni < 4; ++ni)
#pragma unroll
            for (int reg = 0; reg < 4; ++reg) {
                int row = rowBase + wm * 64 + mi * 16 + quad * 4 + reg;
                int col = colBase + wn * 64 + ni * 16 + l15;
                Y[(size_t)row * 1024 + col] = acc[mi][ni][reg];
            }
}

// ---------------------------------------------------------------------------
// Flash attention, 32x32x16 MFMA, St = K Q^T (query = lane -> per-lane softmax
// state). Block pid handles q-tiles {15-pid, pid}: 34 k-tiles per block,
// perfectly balanced (512 blocks = 2/CU).
// SINGLE-barrier double-buffered K-loop: iter kt stages tile kt+1 (regs loaded
// one full iteration earlier) into buf[cur^1], issues loads for tile kt+2,
// computes tile kt from buf[cur]. The compiler's vmcnt drain at the barrier
// then only waits on loads that already had a whole tile of compute to land.
// ---------------------------------------------------------------------------
__global__ __launch_bounds__(256) void flash32(const unsigned short* __restrict__ Q,
                                               const unsigned short* __restrict__ K,
                                               const unsigned short* __restrict__ Vt,
                                               const int* __restrict__ mask,
                                               unsigned short* __restrict__ CTX) {
    __shared__ short lds[16384];           // buf b: Ks=lds+b*8192, Vs=+4096 (shorts)
    __shared__ float biasS[2][64];
    __shared__ int allokS[2];

    const int pid = blockIdx.x;            // 0..7
    const int bh = blockIdx.y;
    const int b = bh >> 4;
    const int tid = threadIdx.x;
    const int w = tid >> 6, lane = tid & 63, l31 = lane & 31, lane5 = lane >> 5;

    const size_t qkBase = (size_t)b * SEQ * D_MODEL + (size_t)(bh & 15) * HEAD_DIM;
    const size_t vtBase = (size_t)bh * HEAD_DIM * SEQ;

    // per-thread staging constants (chunk c = tid + l*256)
    int stp[2], stcc[2], stj[2];
#pragma unroll
    for (int l = 0; l < 2; ++l) {
        int c = tid + l * 256;
        int p = c >> 3, sl = c & 7;
        stp[l] = p;
        stcc[l] = sl ^ (p & 7);                                   // bank swizzle
        stj[l] = (p & 0x33) | ((p & 4) << 1) | ((p & 8) >> 1);    // swap bits 2,3
    }

    for (int phase = 0; phase < 2; ++phase) {
        const int qt = phase ? pid : 15 - pid;
        const int q0 = qt * 128;
        const int iq = q0 + w * 32 + l31;      // this lane's query row

        // Q fragments direct from global: B[n=i=l31][k=lane5*8+jj]
        bf16x8 qf[4];
#pragma unroll
        for (int ks = 0; ks < 4; ++ks)
            qf[ks] = *(const bf16x8*)(Q + qkBase + (size_t)iq * D_MODEL + ks * 16 + lane5 * 8);

        float mv = -INFINITY, lv = 0.f;
        f32x16 Ot[2];
#pragma unroll
        for (int dt = 0; dt < 2; ++dt)
#pragma unroll
            for (int e = 0; e < 16; ++e) Ot[dt][e] = 0.f;

        const int ktmax = 2 * qt + 1;

        uint4 kreg[2], vreg[2];
        int mreg;
        // ---- prologue: load tile0, stage into buf0, load tile1 ----------
#pragma unroll
        for (int l = 0; l < 2; ++l) {
            kreg[l] = *(const uint4*)(K + qkBase + (size_t)stj[l] * D_MODEL + stcc[l] * 8);
            vreg[l] = *(const uint4*)(Vt + vtBase + (size_t)stp[l] * SEQ + stcc[l] * 8);
        }
        mreg = (tid < 64) ? mask[b * SEQ + tid] : 1;
        __syncthreads();                       // protect prev phase epilogue LDS reads
#pragma unroll
        for (int l = 0; l < 2; ++l) {
            int c = tid + l * 256;
            *(uint4*)((char*)lds + c * 16) = kreg[l];              // Ks buf0
            *(uint4*)((char*)lds + 8192 + c * 16) = vreg[l];       // Vs buf0
        }
        if (tid < 64) {
            biasS[0][tid] = mreg ? 0.f : -INFINITY;
            unsigned long long bal = __ballot(mreg != 0);
            if (tid == 0) allokS[0] = (bal == ~0ull) ? 1 : 0;
        }
        if (ktmax >= 1) {
#pragma unroll
            for (int l = 0; l < 2; ++l) {
                kreg[l] = *(const uint4*)(K + qkBase + (size_t)(64 + stj[l]) * D_MODEL + stcc[l] * 8);
                vreg[l] = *(const uint4*)(Vt + vtBase + (size_t)stp[l] * SEQ + 64 + stcc[l] * 8);
            }
            mreg = (tid < 64) ? mask[b * SEQ + 64 + tid] : 1;
        }

        for (int kt = 0; kt <= ktmax; ++kt) {
            const int k0 = kt * 64;
            const int cur = kt & 1;
            __syncthreads();               // buf[cur] visible; buf[cur^1] reads done

            if (kt < ktmax) {              // stage tile kt+1 into buf[cur^1]
                const int nb = (cur ^ 1) * 16384;   // byte offset of next buf
#pragma unroll
                for (int l = 0; l < 2; ++l) {
                    int c = tid + l * 256;
                    *(uint4*)((char*)lds + nb + c * 16) = kreg[l];
                    *(uint4*)((char*)lds + nb + 8192 + c * 16) = vreg[l];
                }
                if (tid < 64) {
                    biasS[cur ^ 1][tid] = mreg ? 0.f : -INFINITY;
                    unsigned long long bal = __ballot(mreg != 0);
                    if (tid == 0) allokS[cur ^ 1] = (bal == ~0ull) ? 1 : 0;
                }
            }
            if (kt + 1 < ktmax) {          // issue loads for tile kt+2
                const int kn = k0 + 128;
#pragma unroll
                for (int l = 0; l < 2; ++l) {
                    kreg[l] = *(const uint4*)(K + qkBase + (size_t)(kn + stj[l]) * D_MODEL + stcc[l] * 8);
                    vreg[l] = *(const uint4*)(Vt + vtBase + (size_t)stp[l] * SEQ + kn + stcc[l] * 8);
                }
                mreg = (tid < 64) ? mask[b * SEQ + kn + tid] : 1;
            }

            if (64 * kt > q0 + 32 * w + 31) continue;   // wave-uniform: above causal diag

            const short* Ks = lds + cur * 8192;
            const short* Vs = lds + cur * 8192 + 4096;

            // ---- St = K Q^T (8 MFMAs) -----------------------------------
            f32x16 St[2];
#pragma unroll
            for (int T = 0; T < 2; ++T)
#pragma unroll
                for (int e = 0; e < 16; ++e) St[T][e] = 0.f;
#pragma unroll
            for (int T = 0; T < 2; ++T)
#pragma unroll
                for (int ks = 0; ks < 4; ++ks) {
                    int p = T * 32 + l31;
                    int slot = (ks * 2 + lane5) ^ (p & 7);
                    bf16x8 a = *(const bf16x8*)&Ks[p * 64 + slot * 8];
                    St[T] = __builtin_amdgcn_mfma_f32_32x32x16_bf16(a, qf[ks], St[T], 0, 0, 0);
                }

            // ---- masking ------------------------------------------------
            const bool partial = (k0 + 63 > q0 + 32 * w);
            if (partial) {
#pragma unroll
                for (int T = 0; T < 2; ++T)
#pragma unroll
                    for (int r = 0; r < 16; ++r) {
                        int j = k0 + 32 * T + 16 * (r >> 3) + 8 * lane5 + (r & 7);
                        if (j > iq) St[T][r] = -INFINITY;
                    }
            }
            if (!allokS[cur]) {
#pragma unroll
                for (int T = 0; T < 2; ++T)
#pragma unroll
                    for (int r = 0; r < 16; ++r)
                        St[T][r] += biasS[cur][32 * T + 16 * (r >> 3) + 8 * lane5 + (r & 7)];
            }

            // ---- online softmax (per-lane state; pairwise-tree reduce) --
            float mx[8];
#pragma unroll
            for (int i = 0; i < 8; ++i)
                mx[i] = fmaxf(fmaxf(St[0][i], St[0][i + 8]), fmaxf(St[1][i], St[1][i + 8]));
#pragma unroll
            for (int i = 0; i < 4; ++i) mx[i] = fmaxf(mx[i], mx[i + 4]);
            float rm = fmaxf(fmaxf(mx[0], mx[1]), fmaxf(mx[2], mx[3]));
            rm = fmaxf(rm, __shfl_xor(rm, 32));
            float mn = fmaxf(mv, rm);
            float al = (mv > -INFINITY) ? exp2f(mv - mn) : 0.f;
            float sm[4] = {0.f, 0.f, 0.f, 0.f};
#pragma unroll
            for (int T = 0; T < 2; ++T)
#pragma unroll
                for (int r = 0; r < 16; ++r) {
                    float pv = (St[T][r] > -INFINITY) ? exp2f(St[T][r] - mn) : 0.f;
                    St[T][r] = pv;
                    sm[r & 3] += pv;
                }
            float rs = (sm[0] + sm[1]) + (sm[2] + sm[3]);
            rs += __shfl_xor(rs, 32);
            lv = lv * al + rs;
            mv = mn;
#pragma unroll
            for (int dt = 0; dt < 2; ++dt)
#pragma unroll
                for (int e = 0; e < 16; ++e) Ot[dt][e] *= al;

            // ---- pack P (regs already in B-fragment order) --------------
            bf16x8 pf[4];
#pragma unroll
            for (int t = 0; t < 4; ++t) {
                int T = t >> 1, hb = t & 1;
#pragma unroll
                for (int jj = 0; jj < 8; ++jj)
                    pf[t][jj] = (short)f2bu_fast(St[T][hb * 8 + jj]);
            }

            // ---- Ot += V^T P^T (8 MFMAs) --------------------------------
#pragma unroll
            for (int dt = 0; dt < 2; ++dt)
#pragma unroll
                for (int t = 0; t < 4; ++t) {
                    int p = dt * 32 + l31;
                    int slot = (t * 2 + lane5) ^ (p & 7);
                    bf16x8 a = *(const bf16x8*)&Vs[p * 64 + slot * 8];
                    Ot[dt] = __builtin_amdgcn_mfma_f32_32x32x16_bf16(a, pf[t], Ot[dt], 0, 0, 0);
                }
        }

        // ---- epilogue: normalize, transpose via LDS, coalesced store ----
        __syncthreads();                       // all waves done with both buffers
        const float inv = 1.f / lv;
#pragma unroll
        for (int dt = 0; dt < 2; ++dt)
#pragma unroll
            for (int k = 0; k < 8; ++k) {
                int r0 = 2 * k;
                int d = (r0 & 3) + 4 * lane5 + 8 * (r0 >> 2) + 32 * dt;
                unsigned lo = f2bu(Ot[dt][r0] * inv);
                unsigned hi = f2bu(Ot[dt][r0 + 1] * inv);
                *(unsigned*)&lds[(w * 32 + l31) * 72 + d] = lo | (hi << 16);
            }
        __syncthreads();
#pragma unroll
        for (int k = 0; k < 4; ++k) {
            int id = tid + k * 256;
            int r = id >> 3, cc = id & 7;
            uint4 v = *(const uint4*)&lds[r * 72 + cc * 8];
            *(uint4*)(CTX + qkBase + (size_t)(q0 + r) * D_MODEL + cc * 8) = v;
        }
        // next phase's prologue __syncthreads protects these LDS reads
    }
}

// ---------------------------------------------------------------------------
extern "C" void kernel_launch(void* const* d_in, const int* in_sizes, int n_in,
                              void* d_out, int out_size, void* d_ws, size_t ws_size,
                              hipStream_t stream) {
    const float* x  = (const float*)d_in[0];
    const int* mask = (const int*)d_in[1];
    const float* wq = (const float*)d_in[2];
    const float* wk = (const float*)d_in[3];
    const float* wv = (const float*)d_in[4];
    const float* wo = (const float*)d_in[5];
    float* out = (float*)d_out;

    const size_t NE = (size_t)M_TOTAL * D_MODEL;
    const size_t WE = (size_t)D_MODEL * D_MODEL;
    unsigned short* ws  = (unsigned short*)d_ws;
    unsigned short* xb  = ws;
    unsigned short* wqb = xb + NE;
    unsigned short* wkb = wqb + WE;
    unsigned short* wvb = wkb + WE;
    unsigned short* wob = wvb + WE;
    unsigned short* Qb  = wob + WE;
    unsigned short* Kb  = Qb + NE;
    unsigned short* Vtb = Kb + NE;
    unsigned short* CTX = Vtb + NE;

    cast_all<<<(int)((NE + 4 * WE) / 4 / 256), 256, 0, stream>>>(x, wq, wk, wv, wo, ws);

    qkv_gemm<<<dim3(24, M_TOTAL / 128), 256, 0, stream>>>(xb, wqb, wkb, wvb, Qb, Kb, Vtb);

    flash32<<<dim3(8, BATCH * N_HEADS), 256, 0, stream>>>(Qb, Kb, Vtb, mask, CTX);

    out_gemm<<<dim3(D_MODEL / 128, M_TOTAL / 128), 256, 0, stream>>>(CTX, wob, out);
}